// Round 7
// baseline (575.891 us; speedup 1.0000x reference)
//
#include <hip/hip_runtime.h>
#include <hip/hip_bf16.h>
#include <stdint.h>

#define NVOX 131072
#define CCH  128
#define EPSV 1e-4f

typedef __bf16 bf16_t;
typedef bf16_t bf16x8 __attribute__((ext_vector_type(8)));
typedef bf16_t bf16x4 __attribute__((ext_vector_type(4)));
typedef float  f32x4  __attribute__((ext_vector_type(4)));

__device__ __forceinline__ void async16(void* lds, const void* g) {
    __builtin_amdgcn_global_load_lds(
        (const __attribute__((address_space(1))) uint32_t*)g,
        (__attribute__((address_space(3))) uint32_t*)lds, 16, 0, 0);
}

// ---------- prep: features f32 -> bf16 ----------
__global__ void k_prep_feat(const float* __restrict__ f, bf16_t* __restrict__ fb) {
    int i = blockIdx.x * 256 + threadIdx.x;      // over N*C/4 = 4194304 exactly
    const float4* f4 = (const float4*)f;
    float4 v = f4[i];
    bf16x4 o;
    o[0] = (bf16_t)v.x; o[1] = (bf16_t)v.y; o[2] = (bf16_t)v.z; o[3] = (bf16_t)v.w;
    ((bf16x4*)fb)[i] = o;
}

// ---------- prep: W [27,Ci,Co] f32 -> W^T [k][co][ci] bf16 (3 layers);
// ---------- block 81 also zeroes pad rows + stats ----------
__global__ void k_prep_w(const float* __restrict__ w0, const float* __restrict__ w1,
                         const float* __restrict__ w2, bf16_t* __restrict__ wbt,
                         bf16_t* featb, bf16_t* xb1, bf16_t* xb2, float* stats) {
    int blk = blockIdx.x;                // 0..81
    if (blk == 81) {
        int t = threadIdx.x;
        if (t < 128) {
            featb[(size_t)NVOX * CCH + t] = (bf16_t)0.0f;
            xb1[(size_t)NVOX * CCH + t]   = (bf16_t)0.0f;
            xb2[(size_t)NVOX * CCH + t]   = (bf16_t)0.0f;
        }
        for (int i = t; i < 768; i += 256) stats[i] = 0.0f;
        return;
    }
    int layer = blk / 27, k = blk % 27;
    const float* w = (layer == 0 ? w0 : (layer == 1 ? w1 : w2)) + k * 16384;
    __shared__ bf16_t tile[128][132];
    for (int e = threadIdx.x; e < 16384; e += 256) {
        int ci = e >> 7, co = e & 127;
        tile[co][ci] = (bf16_t)w[e];
    }
    __syncthreads();
    bf16_t* out = wbt + (size_t)blk * 16384;
    for (int e = threadIdx.x; e < 16384; e += 256) {
        int co = e >> 7, ci = e & 127;
        out[e] = tile[co][ci];
    }
}

// ---------- conv: gather-GEMM 128x128 tile, 64-ci K-chunks ----------
// r6 structure (offs table, two __syncthreads per chunk, compiler-scheduled,
// VGPR<=64 / 3 blocks/CU) with ONE change: K-chunk 32 -> 64 ci. The exposed
// gather-drain (vmcnt(0) before barrier) is paid 54x instead of 108x, with
// 2x MFMA+ds_read amortizing each. Staged rows are 128B wide; swizzle adapted:
// source 16B slot (l&7)^(l>>3), read col ((s*4+lq)^(lrow&7))<<4 (same
// involution family HW-validated in r6).
__global__ __launch_bounds__(256, 3) void k_conv(
        const bf16_t* __restrict__ featb,   // (N+1) x 128 bf16
        const bf16_t* __restrict__ wbt,     // 27 x 128co x 128ci bf16
        const int* __restrict__ nbr,        // N x 27 int32
        float* __restrict__ out,            // N x 128 f32
        float* __restrict__ stat)           // [0..127]=sum, [128..255]=sumsq
{
    __shared__ uint32_t offs[27 * 128];     // 13824 B
    __shared__ bf16_t smA[128 * 64];        // 16384 B: 128 rows x 128 B
    __shared__ bf16_t smB[128 * 64];        // 16384 B
    __shared__ float ssum[128], ssq[128];   // 1024 B   (total 47616)

    const int tid = threadIdx.x;
    const int m0 = blockIdx.x << 7;

    if (tid < 128) { ssum[tid] = 0.0f; ssq[tid] = 0.0f; }

    for (int e = tid; e < 27 * 128; e += 256) {
        int row = e / 27, k = e - row * 27;
        int idx = nbr[(size_t)(m0 + row) * 27 + k];
        offs[(k << 7) + row] = ((uint32_t)(idx < 0 ? NVOX : idx)) << 8;  // byte offset
    }
    __syncthreads();

    const int l = tid & 63, w = tid >> 6;
    const int wm = w >> 1, wn = w & 1;
    const int lrow = l & 15, lq = l >> 4;

    // staging lane constants: per async16, lane l writes LDS byte base+l*16,
    // i.e. row = base/128 + (l>>3), slot = l&7. Source must hold the chunk
    // that belongs at that slot under the involution slot' = slot ^ (row&7),
    // and row&7 == l>>3 for all staging calls here.
    const int lhi   = l >> 3;
    const int laneA = ((l & 7) ^ lhi) << 4;          // swizzled slot offset
    const int laneB = (lhi << 8) + laneA;            // + within-group row*256

    char* dstA = (char*)smA + (w << 10);             // wave-uniform (+q*4096)
    char* dstB = (char*)smB + (w << 10);

    const char* fbase = (const char*)featb;
    const char* wbase = (const char*)wbt;

    f32x4 acc[4][4] = {};

    for (int k = 0; k < 27; ++k) {
        // gather offsets for staged rows q*32 + w*8 + lhi, q = 0..3
        const uint32_t* ok = offs + (k << 7) + (w << 3) + lhi;
        uint32_t ofA0 = ok[0], ofA1 = ok[32], ofA2 = ok[64], ofA3 = ok[96];
        const char* wk = wbase + ((size_t)k << 15) + (w << 11) + laneB;
        #pragma unroll
        for (int h = 0; h < 2; ++h) {
            const int cb = h << 7;                   // ci-half byte offset
            __syncthreads();
            async16(dstA,         fbase + ofA0 + cb + laneA);
            async16(dstA + 4096,  fbase + ofA1 + cb + laneA);
            async16(dstA + 8192,  fbase + ofA2 + cb + laneA);
            async16(dstA + 12288, fbase + ofA3 + cb + laneA);
            async16(dstB,         wk + cb);
            async16(dstB + 4096,  wk + 8192  + cb);
            async16(dstB + 8192,  wk + 16384 + cb);
            async16(dstB + 12288, wk + 24576 + cb);
            __syncthreads();

            #pragma unroll
            for (int s = 0; s < 2; ++s) {
                bf16x8 af[4], bfr[4];
                const int colx = (((s << 2) + lq) ^ (lrow & 7)) << 4;
                #pragma unroll
                for (int i = 0; i < 4; ++i) {
                    af[i]  = *(const bf16x8*)((const char*)smA +
                              (((wm << 6) + (i << 4) + lrow) << 7) + colx);
                    bfr[i] = *(const bf16x8*)((const char*)smB +
                              (((wn << 6) + (i << 4) + lrow) << 7) + colx);
                }
                #pragma unroll
                for (int i = 0; i < 4; ++i)
                    #pragma unroll
                    for (int j = 0; j < 4; ++j)
                        acc[i][j] = __builtin_amdgcn_mfma_f32_16x16x32_bf16(
                            af[i], bfr[j], acc[i][j], 0, 0, 0);
            }
        }
    }

    // epilogue: store + per-channel stats
    float csum[4] = {0, 0, 0, 0}, csq[4] = {0, 0, 0, 0};
    #pragma unroll
    for (int j = 0; j < 4; ++j) {
        int col = (wn << 6) + (j << 4) + lrow;
        #pragma unroll
        for (int i = 0; i < 4; ++i) {
            int grow = m0 + (wm << 6) + (i << 4) + (lq << 2);
            #pragma unroll
            for (int r = 0; r < 4; ++r) {
                float v = acc[i][j][r];
                out[(size_t)(grow + r) * CCH + col] = v;
                csum[j] += v;
                csq[j]  += v * v;
            }
        }
    }
    #pragma unroll
    for (int j = 0; j < 4; ++j) {
        csum[j] += __shfl_xor(csum[j], 16, 64);
        csum[j] += __shfl_xor(csum[j], 32, 64);
        csq[j]  += __shfl_xor(csq[j], 16, 64);
        csq[j]  += __shfl_xor(csq[j], 32, 64);
    }
    if (lq == 0) {
        #pragma unroll
        for (int j = 0; j < 4; ++j) {
            int col = (wn << 6) + (j << 4) + lrow;
            atomicAdd(&ssum[col], csum[j]);
            atomicAdd(&ssq[col],  csq[j]);
        }
    }
    __syncthreads();
    if (tid < 128) {
        atomicAdd(&stat[tid],       ssum[tid]);
        atomicAdd(&stat[128 + tid], ssq[tid]);
    }
}

// ---------- BN + LeakyReLU -> bf16 next-layer input ----------
__global__ void k_bnact(const float* __restrict__ x, const float* __restrict__ stat,
                        const float* __restrict__ g, const float* __restrict__ b,
                        bf16_t* __restrict__ out, float slope) {
    __shared__ float sc[128], sh[128];
    int tid = threadIdx.x;
    if (tid < 128) {
        float mu  = stat[tid] * (1.0f / NVOX);
        float var = stat[128 + tid] * (1.0f / NVOX) - mu * mu;
        float inv = rsqrtf(var + EPSV);
        float s = g[tid] * inv;
        sc[tid] = s;
        sh[tid] = b[tid] - mu * s;
    }
    __syncthreads();
    int i = blockIdx.x * 256 + tid;              // over N*C/4
    float4 v = ((const float4*)x)[i];
    int c = (i << 2) & 127;
    float y0 = v.x * sc[c]     + sh[c];
    float y1 = v.y * sc[c + 1] + sh[c + 1];
    float y2 = v.z * sc[c + 2] + sh[c + 2];
    float y3 = v.w * sc[c + 3] + sh[c + 3];
    y0 = y0 >= 0.0f ? y0 : slope * y0;
    y1 = y1 >= 0.0f ? y1 : slope * y1;
    y2 = y2 >= 0.0f ? y2 : slope * y2;
    y3 = y3 >= 0.0f ? y3 : slope * y3;
    bf16x4 o;
    o[0] = (bf16_t)y0; o[1] = (bf16_t)y1; o[2] = (bf16_t)y2; o[3] = (bf16_t)y3;
    ((bf16x4*)out)[i] = o;
}

// ---------- BN3 + residual + LeakyReLU(1/3) -> f32 d_out ----------
__global__ void k_final(const float* __restrict__ x, const float* __restrict__ stat,
                        const float* __restrict__ g, const float* __restrict__ b,
                        const bf16_t* __restrict__ res, float* __restrict__ out) {
    __shared__ float sc[128], sh[128];
    int tid = threadIdx.x;
    if (tid < 128) {
        float mu  = stat[tid] * (1.0f / NVOX);
        float var = stat[128 + tid] * (1.0f / NVOX) - mu * mu;
        float inv = rsqrtf(var + EPSV);
        float s = g[tid] * inv;
        sc[tid] = s;
        sh[tid] = b[tid] - mu * s;
    }
    __syncthreads();
    int i = blockIdx.x * 256 + tid;
    float4 v = ((const float4*)x)[i];
    bf16x4 r = ((const bf16x4*)res)[i];
    int c = (i << 2) & 127;
    float y0 = v.x * sc[c]     + sh[c]     + (float)r[0];
    float y1 = v.y * sc[c + 1] + sh[c + 1] + (float)r[1];
    float y2 = v.z * sc[c + 2] + sh[c + 2] + (float)r[2];
    float y3 = v.w * sc[c + 3] + sh[c + 3] + (float)r[3];
    const float k3 = 1.0f / 3.0f;
    y0 = y0 >= 0.0f ? y0 : k3 * y0;
    y1 = y1 >= 0.0f ? y1 : k3 * y1;
    y2 = y2 >= 0.0f ? y2 : k3 * y2;
    y3 = y3 >= 0.0f ? y3 : k3 * y3;
    float4 o; o.x = y0; o.y = y1; o.z = y2; o.w = y3;
    ((float4*)out)[i] = o;
}

extern "C" void kernel_launch(void* const* d_in, const int* in_sizes, int n_in,
                              void* d_out, int out_size, void* d_ws, size_t ws_size,
                              hipStream_t stream) {
    (void)in_sizes; (void)n_in; (void)out_size; (void)ws_size;
    const float* features = (const float*)d_in[0];
    const int*   nbr      = (const int*)d_in[1];
    const float* w1 = (const float*)d_in[2];
    const float* w2 = (const float*)d_in[3];
    const float* w3 = (const float*)d_in[4];
    const float* g1 = (const float*)d_in[5];
    const float* b1 = (const float*)d_in[6];
    const float* g2 = (const float*)d_in[7];
    const float* b2 = (const float*)d_in[8];
    const float* g3 = (const float*)d_in[9];
    const float* b3 = (const float*)d_in[10];

    char* ws = (char*)d_ws;
    const size_t SZ_FB = (size_t)(NVOX + 1) * CCH * 2;   // bf16 buffer w/ zero row
    bf16_t* featb    = (bf16_t*)(ws);
    bf16_t* xb1      = (bf16_t*)(ws + SZ_FB);
    bf16_t* xb2      = (bf16_t*)(ws + 2 * SZ_FB);
    float*  conv_out = (float*)(ws + 3 * SZ_FB);
    bf16_t* wbt      = (bf16_t*)(ws + 3 * SZ_FB + (size_t)NVOX * CCH * 4);
    float*  stats    = (float*)(ws + 3 * SZ_FB + (size_t)NVOX * CCH * 4
                                + (size_t)3 * 27 * 128 * 128 * 2);

    k_prep_feat<<<16384, 256, 0, stream>>>(features, featb);
    k_prep_w<<<82, 256, 0, stream>>>(w1, w2, w3, wbt, featb, xb1, xb2, stats);

    k_conv<<<1024, 256, 0, stream>>>(featb, wbt, nbr, conv_out, stats);
    k_bnact<<<16384, 256, 0, stream>>>(conv_out, stats, g1, b1, xb1, 0.05f);

    k_conv<<<1024, 256, 0, stream>>>(xb1, wbt + (size_t)27 * 16384, nbr, conv_out, stats + 256);
    k_bnact<<<16384, 256, 0, stream>>>(conv_out, stats + 256, g2, b2, xb2, 0.05f);

    k_conv<<<1024, 256, 0, stream>>>(xb2, wbt + (size_t)2 * 27 * 16384, nbr, conv_out, stats + 512);
    k_final<<<16384, 256, 0, stream>>>(conv_out, stats + 512, g3, b3, xb1, (float*)d_out);
}

// Round 8
// 531.019 us; speedup vs baseline: 1.0845x; 1.0845x over previous
//
#include <hip/hip_runtime.h>
#include <hip/hip_bf16.h>
#include <stdint.h>

#define NVOX 131072
#define CCH  128
#define EPSV 1e-4f

typedef __bf16 bf16_t;
typedef bf16_t bf16x8 __attribute__((ext_vector_type(8)));
typedef bf16_t bf16x4 __attribute__((ext_vector_type(4)));
typedef float  f32x4  __attribute__((ext_vector_type(4)));

__device__ __forceinline__ void async16(void* lds, const void* g) {
    __builtin_amdgcn_global_load_lds(
        (const __attribute__((address_space(1))) uint32_t*)g,
        (__attribute__((address_space(3))) uint32_t*)lds, 16, 0, 0);
}

// ---------- prep: features f32 -> bf16 ----------
__global__ void k_prep_feat(const float* __restrict__ f, bf16_t* __restrict__ fb) {
    int i = blockIdx.x * 256 + threadIdx.x;      // over N*C/4 = 4194304 exactly
    const float4* f4 = (const float4*)f;
    float4 v = f4[i];
    bf16x4 o;
    o[0] = (bf16_t)v.x; o[1] = (bf16_t)v.y; o[2] = (bf16_t)v.z; o[3] = (bf16_t)v.w;
    ((bf16x4*)fb)[i] = o;
}

// ---------- prep: W [27,Ci,Co] f32 -> W^T [k][co][ci] bf16 (3 layers);
// ---------- block 81 also zeroes pad rows + stats ----------
__global__ void k_prep_w(const float* __restrict__ w0, const float* __restrict__ w1,
                         const float* __restrict__ w2, bf16_t* __restrict__ wbt,
                         bf16_t* featb, bf16_t* xb1, bf16_t* xb2, float* stats) {
    int blk = blockIdx.x;                // 0..81
    if (blk == 81) {
        int t = threadIdx.x;
        if (t < 128) {
            featb[(size_t)NVOX * CCH + t] = (bf16_t)0.0f;
            xb1[(size_t)NVOX * CCH + t]   = (bf16_t)0.0f;
            xb2[(size_t)NVOX * CCH + t]   = (bf16_t)0.0f;
        }
        for (int i = t; i < 768; i += 256) stats[i] = 0.0f;
        return;
    }
    int layer = blk / 27, k = blk % 27;
    const float* w = (layer == 0 ? w0 : (layer == 1 ? w1 : w2)) + k * 16384;
    __shared__ bf16_t tile[128][132];
    for (int e = threadIdx.x; e < 16384; e += 256) {
        int ci = e >> 7, co = e & 127;
        tile[co][ci] = (bf16_t)w[e];
    }
    __syncthreads();
    bf16_t* out = wbt + (size_t)blk * 16384;
    for (int e = threadIdx.x; e < 16384; e += 256) {
        int co = e >> 7, ci = e & 127;
        out[e] = tile[co][ci];
    }
}

// ---------- conv: gather-GEMM 128x128 tile, bf16 MFMA, + channel stats ----------
// r6 kernel EXACTLY (offs LDS table, two __syncthreads per chunk, T2 swizzle,
// compiler-scheduled, 64 arch VGPR proven) with ONE change:
// __launch_bounds__(256,3) -> (256,4). Forces total unified regs <= 128/wave
// so the HW can place 4 blocks/CU (16 waves) instead of 3. The r6 body's
// live set already fit 64 arch regs, so no spill is expected; failure
// signature (spill) = FETCH/WRITE balloon, as seen in r4.
__global__ __launch_bounds__(256, 4) void k_conv(
        const bf16_t* __restrict__ featb,   // (N+1) x 128 bf16
        const bf16_t* __restrict__ wbt,     // 27 x 128co x 128ci bf16
        const int* __restrict__ nbr,        // N x 27 int32
        float* __restrict__ out,            // N x 128 f32
        float* __restrict__ stat)           // [0..127]=sum, [128..255]=sumsq
{
    __shared__ uint32_t offs[27 * 128];
    __shared__ bf16_t smA[128 * 32];
    __shared__ bf16_t smB[128 * 32];
    __shared__ float ssum[128], ssq[128];

    const int tid = threadIdx.x;
    const int m0 = blockIdx.x << 7;

    if (tid < 128) { ssum[tid] = 0.0f; ssq[tid] = 0.0f; }

    for (int e = tid; e < 27 * 128; e += 256) {
        int row = e / 27, k = e - row * 27;
        int idx = nbr[(size_t)(m0 + row) * 27 + k];
        offs[(k << 7) + row] = ((uint32_t)(idx < 0 ? NVOX : idx)) << 8;  // byte offset
    }
    __syncthreads();

    const int l = tid & 63, w = tid >> 6;
    const int wm = w >> 1, wn = w & 1;
    const int lrow = l & 15, lq = l >> 4;

    const int srow = (w << 4) + (l >> 2);   // staging row 0..63
    // source-side swizzle: slot (l&3) of row srow holds chunk (l&3)^((srow>>1)&3);
    // (srow>>1)&3 == (l>>3)&3 for this staging mapping
    const int ssub = (((l & 3) ^ ((l >> 3) & 3)) << 4);
    // read-side swizzle: chunk lq of row R lives at slot lq ^ ((R>>1)&3)
    const int cxor = ((lq ^ ((lrow >> 1) & 3)) << 4);

    char* dstA0 = (char*)smA + (w << 10);
    char* dstA1 = (char*)smA + 4096 + (w << 10);
    char* dstB0 = (char*)smB + (w << 10);
    char* dstB1 = (char*)smB + 4096 + (w << 10);

    const char* fbase = (const char*)featb;
    const char* wbase = (const char*)wbt;

    f32x4 acc[4][4] = {};

    for (int k = 0; k < 27; ++k) {
        uint32_t offA0 = offs[(k << 7) + srow];
        uint32_t offA1 = offs[(k << 7) + srow + 64];
        const char* wk = wbase + ((size_t)k << 15);   // k * 128*128*2
        #pragma unroll
        for (int c = 0; c < 4; ++c) {
            const int cb = c << 6;                    // ci-chunk byte offset
            __syncthreads();
            async16(dstA0, fbase + offA0 + cb + ssub);
            async16(dstA1, fbase + offA1 + cb + ssub);
            async16(dstB0, wk + (srow << 8) + cb + ssub);
            async16(dstB1, wk + ((srow + 64) << 8) + cb + ssub);
            __syncthreads();

            bf16x8 af[4], bfr[4];
            #pragma unroll
            for (int i = 0; i < 4; ++i) {
                af[i]  = *(const bf16x8*)((const char*)smA +
                          ((((wm << 6) + (i << 4) + lrow)) << 6) + cxor);
                bfr[i] = *(const bf16x8*)((const char*)smB +
                          ((((wn << 6) + (i << 4) + lrow)) << 6) + cxor);
            }
            #pragma unroll
            for (int i = 0; i < 4; ++i)
                #pragma unroll
                for (int j = 0; j < 4; ++j)
                    acc[i][j] = __builtin_amdgcn_mfma_f32_16x16x32_bf16(
                        af[i], bfr[j], acc[i][j], 0, 0, 0);
        }
    }

    // epilogue: store + per-channel stats
    float csum[4] = {0, 0, 0, 0}, csq[4] = {0, 0, 0, 0};
    #pragma unroll
    for (int j = 0; j < 4; ++j) {
        int col = (wn << 6) + (j << 4) + lrow;
        #pragma unroll
        for (int i = 0; i < 4; ++i) {
            int grow = m0 + (wm << 6) + (i << 4) + (lq << 2);
            #pragma unroll
            for (int r = 0; r < 4; ++r) {
                float v = acc[i][j][r];
                out[(size_t)(grow + r) * CCH + col] = v;
                csum[j] += v;
                csq[j]  += v * v;
            }
        }
    }
    #pragma unroll
    for (int j = 0; j < 4; ++j) {
        csum[j] += __shfl_xor(csum[j], 16, 64);
        csum[j] += __shfl_xor(csum[j], 32, 64);
        csq[j]  += __shfl_xor(csq[j], 16, 64);
        csq[j]  += __shfl_xor(csq[j], 32, 64);
    }
    if (lq == 0) {
        #pragma unroll
        for (int j = 0; j < 4; ++j) {
            int col = (wn << 6) + (j << 4) + lrow;
            atomicAdd(&ssum[col], csum[j]);
            atomicAdd(&ssq[col],  csq[j]);
        }
    }
    __syncthreads();
    if (tid < 128) {
        atomicAdd(&stat[tid],       ssum[tid]);
        atomicAdd(&stat[128 + tid], ssq[tid]);
    }
}

// ---------- BN + LeakyReLU -> bf16 next-layer input ----------
__global__ void k_bnact(const float* __restrict__ x, const float* __restrict__ stat,
                        const float* __restrict__ g, const float* __restrict__ b,
                        bf16_t* __restrict__ out, float slope) {
    __shared__ float sc[128], sh[128];
    int tid = threadIdx.x;
    if (tid < 128) {
        float mu  = stat[tid] * (1.0f / NVOX);
        float var = stat[128 + tid] * (1.0f / NVOX) - mu * mu;
        float inv = rsqrtf(var + EPSV);
        float s = g[tid] * inv;
        sc[tid] = s;
        sh[tid] = b[tid] - mu * s;
    }
    __syncthreads();
    int i = blockIdx.x * 256 + tid;              // over N*C/4
    float4 v = ((const float4*)x)[i];
    int c = (i << 2) & 127;
    float y0 = v.x * sc[c]     + sh[c];
    float y1 = v.y * sc[c + 1] + sh[c + 1];
    float y2 = v.z * sc[c + 2] + sh[c + 2];
    float y3 = v.w * sc[c + 3] + sh[c + 3];
    y0 = y0 >= 0.0f ? y0 : slope * y0;
    y1 = y1 >= 0.0f ? y1 : slope * y1;
    y2 = y2 >= 0.0f ? y2 : slope * y2;
    y3 = y3 >= 0.0f ? y3 : slope * y3;
    bf16x4 o;
    o[0] = (bf16_t)y0; o[1] = (bf16_t)y1; o[2] = (bf16_t)y2; o[3] = (bf16_t)y3;
    ((bf16x4*)out)[i] = o;
}

// ---------- BN3 + residual + LeakyReLU(1/3) -> f32 d_out ----------
__global__ void k_final(const float* __restrict__ x, const float* __restrict__ stat,
                        const float* __restrict__ g, const float* __restrict__ b,
                        const bf16_t* __restrict__ res, float* __restrict__ out) {
    __shared__ float sc[128], sh[128];
    int tid = threadIdx.x;
    if (tid < 128) {
        float mu  = stat[tid] * (1.0f / NVOX);
        float var = stat[128 + tid] * (1.0f / NVOX) - mu * mu;
        float inv = rsqrtf(var + EPSV);
        float s = g[tid] * inv;
        sc[tid] = s;
        sh[tid] = b[tid] - mu * s;
    }
    __syncthreads();
    int i = blockIdx.x * 256 + tid;
    float4 v = ((const float4*)x)[i];
    bf16x4 r = ((const bf16x4*)res)[i];
    int c = (i << 2) & 127;
    float y0 = v.x * sc[c]     + sh[c]     + (float)r[0];
    float y1 = v.y * sc[c + 1] + sh[c + 1] + (float)r[1];
    float y2 = v.z * sc[c + 2] + sh[c + 2] + (float)r[2];
    float y3 = v.w * sc[c + 3] + sh[c + 3] + (float)r[3];
    const float k3 = 1.0f / 3.0f;
    y0 = y0 >= 0.0f ? y0 : k3 * y0;
    y1 = y1 >= 0.0f ? y1 : k3 * y1;
    y2 = y2 >= 0.0f ? y2 : k3 * y2;
    y3 = y3 >= 0.0f ? y3 : k3 * y3;
    float4 o; o.x = y0; o.y = y1; o.z = y2; o.w = y3;
    ((float4*)out)[i] = o;
}

extern "C" void kernel_launch(void* const* d_in, const int* in_sizes, int n_in,
                              void* d_out, int out_size, void* d_ws, size_t ws_size,
                              hipStream_t stream) {
    (void)in_sizes; (void)n_in; (void)out_size; (void)ws_size;
    const float* features = (const float*)d_in[0];
    const int*   nbr      = (const int*)d_in[1];
    const float* w1 = (const float*)d_in[2];
    const float* w2 = (const float*)d_in[3];
    const float* w3 = (const float*)d_in[4];
    const float* g1 = (const float*)d_in[5];
    const float* b1 = (const float*)d_in[6];
    const float* g2 = (const float*)d_in[7];
    const float* b2 = (const float*)d_in[8];
    const float* g3 = (const float*)d_in[9];
    const float* b3 = (const float*)d_in[10];

    char* ws = (char*)d_ws;
    const size_t SZ_FB = (size_t)(NVOX + 1) * CCH * 2;   // bf16 buffer w/ zero row
    bf16_t* featb    = (bf16_t*)(ws);
    bf16_t* xb1      = (bf16_t*)(ws + SZ_FB);
    bf16_t* xb2      = (bf16_t*)(ws + 2 * SZ_FB);
    float*  conv_out = (float*)(ws + 3 * SZ_FB);
    bf16_t* wbt      = (bf16_t*)(ws + 3 * SZ_FB + (size_t)NVOX * CCH * 4);
    float*  stats    = (float*)(ws + 3 * SZ_FB + (size_t)NVOX * CCH * 4
                                + (size_t)3 * 27 * 128 * 128 * 2);

    k_prep_feat<<<16384, 256, 0, stream>>>(features, featb);
    k_prep_w<<<82, 256, 0, stream>>>(w1, w2, w3, wbt, featb, xb1, xb2, stats);

    k_conv<<<1024, 256, 0, stream>>>(featb, wbt, nbr, conv_out, stats);
    k_bnact<<<16384, 256, 0, stream>>>(conv_out, stats, g1, b1, xb1, 0.05f);

    k_conv<<<1024, 256, 0, stream>>>(xb1, wbt + (size_t)27 * 16384, nbr, conv_out, stats + 256);
    k_bnact<<<16384, 256, 0, stream>>>(conv_out, stats + 256, g2, b2, xb2, 0.05f);

    k_conv<<<1024, 256, 0, stream>>>(xb2, wbt + (size_t)2 * 27 * 16384, nbr, conv_out, stats + 512);
    k_final<<<16384, 256, 0, stream>>>(conv_out, stats + 512, g3, b3, xb1, (float*)d_out);
}

// Round 10
// 521.227 us; speedup vs baseline: 1.1049x; 1.0188x over previous
//
#include <hip/hip_runtime.h>
#include <hip/hip_bf16.h>
#include <stdint.h>

#define NVOX 131072
#define CCH  128
#define EPSV 1e-4f

typedef __bf16 bf16_t;
typedef bf16_t bf16x8 __attribute__((ext_vector_type(8)));
typedef bf16_t bf16x4 __attribute__((ext_vector_type(4)));
typedef float  f32x4  __attribute__((ext_vector_type(4)));

__device__ __forceinline__ void async16(void* lds, const void* g) {
    __builtin_amdgcn_global_load_lds(
        (const __attribute__((address_space(1))) uint32_t*)g,
        (__attribute__((address_space(3))) uint32_t*)lds, 16, 0, 0);
}

// ---------- prep: features f32 -> bf16 ----------
__global__ void k_prep_feat(const float* __restrict__ f, bf16_t* __restrict__ fb) {
    int i = blockIdx.x * 256 + threadIdx.x;      // over N*C/4 = 4194304 exactly
    const float4* f4 = (const float4*)f;
    float4 v = f4[i];
    bf16x4 o;
    o[0] = (bf16_t)v.x; o[1] = (bf16_t)v.y; o[2] = (bf16_t)v.z; o[3] = (bf16_t)v.w;
    ((bf16x4*)fb)[i] = o;
}

// ---------- prep: W [27,Ci,Co] f32 -> W^T [k][co][ci] bf16 (3 layers);
// ---------- block 81 also zeroes pad rows + stats ----------
__global__ void k_prep_w(const float* __restrict__ w0, const float* __restrict__ w1,
                         const float* __restrict__ w2, bf16_t* __restrict__ wbt,
                         bf16_t* featb, bf16_t* xb1, bf16_t* xb2, float* stats) {
    int blk = blockIdx.x;                // 0..81
    if (blk == 81) {
        int t = threadIdx.x;
        if (t < 128) {
            featb[(size_t)NVOX * CCH + t] = (bf16_t)0.0f;
            xb1[(size_t)NVOX * CCH + t]   = (bf16_t)0.0f;
            xb2[(size_t)NVOX * CCH + t]   = (bf16_t)0.0f;
        }
        for (int i = t; i < 768; i += 256) stats[i] = 0.0f;
        return;
    }
    int layer = blk / 27, k = blk % 27;
    const float* w = (layer == 0 ? w0 : (layer == 1 ? w1 : w2)) + k * 16384;
    __shared__ bf16_t tile[128][132];
    for (int e = threadIdx.x; e < 16384; e += 256) {
        int ci = e >> 7, co = e & 127;
        tile[co][ci] = (bf16_t)w[e];
    }
    __syncthreads();
    bf16_t* out = wbt + (size_t)blk * 16384;
    for (int e = threadIdx.x; e < 16384; e += 256) {
        int co = e >> 7, ci = e & 127;
        out[e] = tile[co][ci];
    }
}

// ---------- conv: gather-GEMM 128x128 tile, bf16 MFMA, + channel stats ----------
// r8 k_conv VERBATIM (two __syncthreads per chunk, T2 swizzle, compiler-
// scheduled, VGPR 64, deterministic across r0/r6/r8) with ONE change:
// output stored as bf16 (halves conv WRITE + downstream READ traffic).
// Stats still accumulate from the f32 acc registers, so BN math is unchanged.
// Schedule restructures are closed: r1/r3/r5 lost occupancy, r9 raced
// (raw s_barrier lacks __syncthreads' fence semantics).
__global__ __launch_bounds__(256, 4) void k_conv(
        const bf16_t* __restrict__ featb,   // (N+1) x 128 bf16
        const bf16_t* __restrict__ wbt,     // 27 x 128co x 128ci bf16
        const int* __restrict__ nbr,        // N x 27 int32
        bf16_t* __restrict__ out,           // N x 128 bf16
        float* __restrict__ stat)           // [0..127]=sum, [128..255]=sumsq
{
    __shared__ uint32_t offs[27 * 128];
    __shared__ bf16_t smA[128 * 32];
    __shared__ bf16_t smB[128 * 32];
    __shared__ float ssum[128], ssq[128];

    const int tid = threadIdx.x;
    const int m0 = blockIdx.x << 7;

    if (tid < 128) { ssum[tid] = 0.0f; ssq[tid] = 0.0f; }

    for (int e = tid; e < 27 * 128; e += 256) {
        int row = e / 27, k = e - row * 27;
        int idx = nbr[(size_t)(m0 + row) * 27 + k];
        offs[(k << 7) + row] = ((uint32_t)(idx < 0 ? NVOX : idx)) << 8;  // byte offset
    }
    __syncthreads();

    const int l = tid & 63, w = tid >> 6;
    const int wm = w >> 1, wn = w & 1;
    const int lrow = l & 15, lq = l >> 4;

    const int srow = (w << 4) + (l >> 2);   // staging row 0..63
    // source-side swizzle: slot (l&3) of row srow holds chunk (l&3)^((srow>>1)&3);
    // (srow>>1)&3 == (l>>3)&3 for this staging mapping
    const int ssub = (((l & 3) ^ ((l >> 3) & 3)) << 4);
    // read-side swizzle: chunk lq of row R lives at slot lq ^ ((R>>1)&3)
    const int cxor = ((lq ^ ((lrow >> 1) & 3)) << 4);

    char* dstA0 = (char*)smA + (w << 10);
    char* dstA1 = (char*)smA + 4096 + (w << 10);
    char* dstB0 = (char*)smB + (w << 10);
    char* dstB1 = (char*)smB + 4096 + (w << 10);

    const char* fbase = (const char*)featb;
    const char* wbase = (const char*)wbt;

    f32x4 acc[4][4] = {};

    for (int k = 0; k < 27; ++k) {
        uint32_t offA0 = offs[(k << 7) + srow];
        uint32_t offA1 = offs[(k << 7) + srow + 64];
        const char* wk = wbase + ((size_t)k << 15);   // k * 128*128*2
        #pragma unroll
        for (int c = 0; c < 4; ++c) {
            const int cb = c << 6;                    // ci-chunk byte offset
            __syncthreads();
            async16(dstA0, fbase + offA0 + cb + ssub);
            async16(dstA1, fbase + offA1 + cb + ssub);
            async16(dstB0, wk + (srow << 8) + cb + ssub);
            async16(dstB1, wk + ((srow + 64) << 8) + cb + ssub);
            __syncthreads();

            bf16x8 af[4], bfr[4];
            #pragma unroll
            for (int i = 0; i < 4; ++i) {
                af[i]  = *(const bf16x8*)((const char*)smA +
                          ((((wm << 6) + (i << 4) + lrow)) << 6) + cxor);
                bfr[i] = *(const bf16x8*)((const char*)smB +
                          ((((wn << 6) + (i << 4) + lrow)) << 6) + cxor);
            }
            #pragma unroll
            for (int i = 0; i < 4; ++i)
                #pragma unroll
                for (int j = 0; j < 4; ++j)
                    acc[i][j] = __builtin_amdgcn_mfma_f32_16x16x32_bf16(
                        af[i], bfr[j], acc[i][j], 0, 0, 0);
        }
    }

    // epilogue: store (bf16) + per-channel stats (f32 from acc)
    float csum[4] = {0, 0, 0, 0}, csq[4] = {0, 0, 0, 0};
    #pragma unroll
    for (int j = 0; j < 4; ++j) {
        int col = (wn << 6) + (j << 4) + lrow;
        #pragma unroll
        for (int i = 0; i < 4; ++i) {
            int grow = m0 + (wm << 6) + (i << 4) + (lq << 2);
            #pragma unroll
            for (int r = 0; r < 4; ++r) {
                float v = acc[i][j][r];
                out[(size_t)(grow + r) * CCH + col] = (bf16_t)v;
                csum[j] += v;
                csq[j]  += v * v;
            }
        }
    }
    #pragma unroll
    for (int j = 0; j < 4; ++j) {
        csum[j] += __shfl_xor(csum[j], 16, 64);
        csum[j] += __shfl_xor(csum[j], 32, 64);
        csq[j]  += __shfl_xor(csq[j], 16, 64);
        csq[j]  += __shfl_xor(csq[j], 32, 64);
    }
    if (lq == 0) {
        #pragma unroll
        for (int j = 0; j < 4; ++j) {
            int col = (wn << 6) + (j << 4) + lrow;
            atomicAdd(&ssum[col], csum[j]);
            atomicAdd(&ssq[col],  csq[j]);
        }
    }
    __syncthreads();
    if (tid < 128) {
        atomicAdd(&stat[tid],       ssum[tid]);
        atomicAdd(&stat[128 + tid], ssq[tid]);
    }
}

// ---------- BN + LeakyReLU (bf16 in) -> bf16 next-layer input ----------
__global__ void k_bnact(const bf16_t* __restrict__ x, const float* __restrict__ stat,
                        const float* __restrict__ g, const float* __restrict__ b,
                        bf16_t* __restrict__ out, float slope) {
    __shared__ float sc[128], sh[128];
    int tid = threadIdx.x;
    if (tid < 128) {
        float mu  = stat[tid] * (1.0f / NVOX);
        float var = stat[128 + tid] * (1.0f / NVOX) - mu * mu;
        float inv = rsqrtf(var + EPSV);
        float s = g[tid] * inv;
        sc[tid] = s;
        sh[tid] = b[tid] - mu * s;
    }
    __syncthreads();
    int i = blockIdx.x * 256 + tid;              // over N*C/8 = 2097152
    bf16x8 v = ((const bf16x8*)x)[i];
    int c = (i << 3) & 127;
    bf16x8 o;
    #pragma unroll
    for (int e = 0; e < 8; ++e) {
        float y = (float)v[e] * sc[c + e] + sh[c + e];
        y = y >= 0.0f ? y : slope * y;
        o[e] = (bf16_t)y;
    }
    ((bf16x8*)out)[i] = o;
}

// ---------- BN3 + residual + LeakyReLU(1/3) -> f32 d_out ----------
__global__ void k_final(const bf16_t* __restrict__ x, const float* __restrict__ stat,
                        const float* __restrict__ g, const float* __restrict__ b,
                        const bf16_t* __restrict__ res, float* __restrict__ out) {
    __shared__ float sc[128], sh[128];
    int tid = threadIdx.x;
    if (tid < 128) {
        float mu  = stat[tid] * (1.0f / NVOX);
        float var = stat[128 + tid] * (1.0f / NVOX) - mu * mu;
        float inv = rsqrtf(var + EPSV);
        float s = g[tid] * inv;
        sc[tid] = s;
        sh[tid] = b[tid] - mu * s;
    }
    __syncthreads();
    int i = blockIdx.x * 256 + tid;              // over N*C/8
    bf16x8 v = ((const bf16x8*)x)[i];
    bf16x8 r = ((const bf16x8*)res)[i];
    int c = (i << 3) & 127;
    const float k3 = 1.0f / 3.0f;
    float yy[8];
    #pragma unroll
    for (int e = 0; e < 8; ++e) {
        float y = (float)v[e] * sc[c + e] + sh[c + e] + (float)r[e];
        yy[e] = y >= 0.0f ? y : k3 * y;
    }
    float4 o0, o1;
    o0.x = yy[0]; o0.y = yy[1]; o0.z = yy[2]; o0.w = yy[3];
    o1.x = yy[4]; o1.y = yy[5]; o1.z = yy[6]; o1.w = yy[7];
    ((float4*)out)[2 * i]     = o0;
    ((float4*)out)[2 * i + 1] = o1;
}

extern "C" void kernel_launch(void* const* d_in, const int* in_sizes, int n_in,
                              void* d_out, int out_size, void* d_ws, size_t ws_size,
                              hipStream_t stream) {
    (void)in_sizes; (void)n_in; (void)out_size; (void)ws_size;
    const float* features = (const float*)d_in[0];
    const int*   nbr      = (const int*)d_in[1];
    const float* w1 = (const float*)d_in[2];
    const float* w2 = (const float*)d_in[3];
    const float* w3 = (const float*)d_in[4];
    const float* g1 = (const float*)d_in[5];
    const float* b1 = (const float*)d_in[6];
    const float* g2 = (const float*)d_in[7];
    const float* b2 = (const float*)d_in[8];
    const float* g3 = (const float*)d_in[9];
    const float* b3 = (const float*)d_in[10];

    char* ws = (char*)d_ws;
    const size_t SZ_FB = (size_t)(NVOX + 1) * CCH * 2;   // bf16 buffer w/ zero row
    bf16_t* featb    = (bf16_t*)(ws);
    bf16_t* xb1      = (bf16_t*)(ws + SZ_FB);
    bf16_t* xb2      = (bf16_t*)(ws + 2 * SZ_FB);
    bf16_t* conv_out = (bf16_t*)(ws + 3 * SZ_FB);
    bf16_t* wbt      = (bf16_t*)(ws + 3 * SZ_FB + (size_t)NVOX * CCH * 2);
    float*  stats    = (float*)(ws + 3 * SZ_FB + (size_t)NVOX * CCH * 2
                                + (size_t)3 * 27 * 128 * 128 * 2);

    k_prep_feat<<<16384, 256, 0, stream>>>(features, featb);
    k_prep_w<<<82, 256, 0, stream>>>(w1, w2, w3, wbt, featb, xb1, xb2, stats);

    k_conv<<<1024, 256, 0, stream>>>(featb, wbt, nbr, conv_out, stats);
    k_bnact<<<8192, 256, 0, stream>>>(conv_out, stats, g1, b1, xb1, 0.05f);

    k_conv<<<1024, 256, 0, stream>>>(xb1, wbt + (size_t)27 * 16384, nbr, conv_out, stats + 256);
    k_bnact<<<8192, 256, 0, stream>>>(conv_out, stats + 256, g2, b2, xb2, 0.05f);

    k_conv<<<1024, 256, 0, stream>>>(xb2, wbt + (size_t)2 * 27 * 16384, nbr, conv_out, stats + 512);
    k_final<<<8192, 256, 0, stream>>>(conv_out, stats + 512, g3, b3, xb1, (float*)d_out);
}